// Round 2
// baseline (9227.750 us; speedup 1.0000x reference)
//
#include <hip/hip_runtime.h>
#include <stdint.h>

// Farthest Point Sampling, persistent-kernel formulation.
// B=32 batches, N=131072 points, 1024 samples.
// 8 chunk-blocks per batch (256 blocks x 512 threads), coords in VGPRs,
// running min-dist in LDS, per-round cross-block sync via device-scope atomics.

#define NB       32
#define NPTS     131072
#define NSAMP    1024
#define CHUNKS   8
#define THREADS  512
#define PPT      (NPTS / (CHUNKS * THREADS))   // 32 points per thread
#define CHUNK_PTS (NPTS / CHUNKS)              // 16384 points per block
#define BIGF     1e10f

// ws layout: [0, 8192)  per-batch arrival counters, 256B stride (padding vs false sharing)
//            [8192, 12288) keys[2][NB][CHUNKS]  (parity double-buffered argmax partials)
#define CNT_STRIDE_U32 64

// __launch_bounds__(512, 2): 2 waves/EU floor -> 256-VGPR cap, no spill risk for
// the 96-reg coord arrays. LDS (64 KB) caps us at 2 blocks/CU anyway; deadlock
// safety needs only 1 block/CU x 256 CUs = 256 blocks co-resident.
__global__ __launch_bounds__(THREADS, 2)
void fps_kernel(const float* __restrict__ pts,
                float* __restrict__ out,
                unsigned int* __restrict__ cnt,
                unsigned long long* __restrict__ keys)
{
    #pragma clang fp contract(off)   // match XLA's un-contracted (dx^2 + dy^2) + dz^2

    const int b = blockIdx.x & (NB - 1);   // batch: consecutive blockIdx -> consecutive batch
    const int c = blockIdx.x >> 5;         // chunk: same-batch blocks are stride-32 => same XCD (mod 8)
    const int t = threadIdx.x;

    __shared__ float ldist[CHUNK_PTS];         // 64 KB running min-dist
    __shared__ float wbv[THREADS / 64];
    __shared__ int   wbi[THREADS / 64];
    __shared__ float bc_x, bc_y, bc_z;

    const float* bpts = pts + (size_t)b * NPTS * 3;

    // Load this thread's 32 points into registers (coalesced: lane-consecutive n).
    float x[PPT], y[PPT], z[PPT];
    #pragma unroll
    for (int i = 0; i < PPT; ++i) {
        const int n = c * CHUNK_PTS + i * THREADS + t;
        x[i] = bpts[3 * n + 0];
        y[i] = bpts[3 * n + 1];
        z[i] = bpts[3 * n + 2];
        ldist[i * THREADS + t] = BIGF;
    }

    // First selected point is index 0 (reference emits init_idx=0 first).
    float px = bpts[0], py = bpts[1], pz = bpts[2];
    if (c == 0 && t == 0) {
        out[(size_t)b * NSAMP * 3 + 0] = px;
        out[(size_t)b * NSAMP * 3 + 1] = py;
        out[(size_t)b * NSAMP * 3 + 2] = pz;
    }
    __syncthreads();

    unsigned int* cntb = cnt + b * CNT_STRIDE_U32;

    for (int s = 1; s < NSAMP; ++s) {
        // --- distance update + thread-local argmax (all static indices) ---
        float bv = -1.0f;
        int   bi = 0;
        #pragma unroll
        for (int i = 0; i < PPT; ++i) {
            const float dx = x[i] - px;
            const float dy = y[i] - py;
            const float dz = z[i] - pz;
            float d = dx * dx;
            d = d + dy * dy;
            d = d + dz * dz;
            const float od = ldist[i * THREADS + t];
            const float nd = fminf(od, d);
            ldist[i * THREADS + t] = nd;
            if (nd > bv) { bv = nd; bi = c * CHUNK_PTS + i * THREADS + t; }
            // strict '>' keeps earliest (lowest) index within the thread
        }

        // --- wave argmax (64 lanes), tie -> lower global index ---
        #pragma unroll
        for (int off = 32; off > 0; off >>= 1) {
            const float ov = __shfl_xor(bv, off);
            const int   oi = __shfl_xor(bi, off);
            if (ov > bv || (ov == bv && oi < bi)) { bv = ov; bi = oi; }
        }
        if ((t & 63) == 0) { wbv[t >> 6] = bv; wbi[t >> 6] = bi; }
        __syncthreads();

        if (t == 0) {
            // --- block argmax over 8 waves ---
            float gv = wbv[0]; int gi = wbi[0];
            #pragma unroll
            for (int w = 1; w < THREADS / 64; ++w) {
                const float ov = wbv[w]; const int oi = wbi[w];
                if (ov > gv || (ov == gv && oi < gi)) { gv = ov; gi = oi; }
            }
            // key: high 32 = float bits (monotone for d>=0), low 32 = ~idx (tie -> lower idx)
            const unsigned long long key =
                ((unsigned long long)__float_as_uint(gv) << 32) |
                (unsigned long long)(0xFFFFFFFFu - (unsigned)gi);

            unsigned long long* kslot = keys + ((size_t)(s & 1) * NB + b) * CHUNKS;
            __hip_atomic_store(&kslot[c], key, __ATOMIC_RELAXED, __HIP_MEMORY_SCOPE_AGENT);
            __hip_atomic_fetch_add(cntb, 1u, __ATOMIC_ACQ_REL, __HIP_MEMORY_SCOPE_AGENT);

            const unsigned int target = (unsigned)(CHUNKS * s);
            while (__hip_atomic_load(cntb, __ATOMIC_ACQUIRE, __HIP_MEMORY_SCOPE_AGENT) < target) {
                __builtin_amdgcn_s_sleep(1);
            }

            // --- global (per-batch) argmax over 8 chunk partials ---
            unsigned long long gkey = 0;
            #pragma unroll
            for (int cc = 0; cc < CHUNKS; ++cc) {
                const unsigned long long k2 =
                    __hip_atomic_load(&kslot[cc], __ATOMIC_RELAXED, __HIP_MEMORY_SCOPE_AGENT);
                if (k2 > gkey) gkey = k2;
            }
            const int widx = (int)(0xFFFFFFFFu - (unsigned)(gkey & 0xFFFFFFFFull));

            // winner coords from read-only global points (L2/L3-hot)
            const float wx = bpts[3 * (size_t)widx + 0];
            const float wy = bpts[3 * (size_t)widx + 1];
            const float wz = bpts[3 * (size_t)widx + 2];
            bc_x = wx; bc_y = wy; bc_z = wz;
            if (c == 0) {
                const size_t o = ((size_t)b * NSAMP + s) * 3;
                out[o + 0] = wx; out[o + 1] = wy; out[o + 2] = wz;
            }
        }
        __syncthreads();
        px = bc_x; py = bc_y; pz = bc_z;
    }
}

extern "C" void kernel_launch(void* const* d_in, const int* in_sizes, int n_in,
                              void* d_out, int out_size, void* d_ws, size_t ws_size,
                              hipStream_t stream)
{
    const float* pts = (const float*)d_in[0];
    float* out = (float*)d_out;

    unsigned int* cnt = (unsigned int*)d_ws;                               // 8192 B
    unsigned long long* keys = (unsigned long long*)((char*)d_ws + 8192);  // 4096 B

    // counters must start at 0 every launch (ws is poisoned 0xAA); keys need no
    // init (parity double-buffered, always written before read).
    hipMemsetAsync(d_ws, 0, 8192, stream);

    fps_kernel<<<dim3(NB * CHUNKS), dim3(THREADS), 0, stream>>>(pts, out, cnt, keys);
}

// Round 6
// 3170.659 us; speedup vs baseline: 2.9104x; 2.9104x over previous
//
#include <hip/hip_runtime.h>
#include <stdint.h>

// Farthest Point Sampling, persistent kernel. B=32, N=131072, S=1024.
// 8 chunk-blocks per batch (256 blocks x 512 threads). Coords AND running
// min-dist in registers. Cross-block rendezvous is FENCE-FREE: one relaxed
// agent-scope u64 key per (batch,chunk), parity double-buffered, with the
// round number embedded in the low bits as its own ready-flag.

#define NB        32
#define NPTS      131072
#define NSAMP     1024
#define CHUNKS    8
#define THREADS   512
#define PPT       32          // NPTS / (CHUNKS*THREADS)
#define CHUNK_PTS 16384       // NPTS / CHUNKS
#define BIGF      1e10f
#define SEQ_MASK  0x7FFFull   // 15 seq bits; s <= 1023; 0xAA poison seq = 0x2AAA never matches

// key layout: [dist_bits:32][NPTS-1-idx:17][seq:15]
// u64 max-compare == (dist desc, then idx asc); seq equal across slots of a round.

__global__ __launch_bounds__(THREADS, 2)   // 2 waves/EU floor -> 256-VGPR cap, no scratch spill
void fps_kernel(const float* __restrict__ pts,
                float* __restrict__ out,
                unsigned long long* __restrict__ keys)
{
    #pragma clang fp contract(off)   // match XLA's un-contracted (dx^2 + dy^2) + dz^2 (absmax=0 in R2)

    const int b = blockIdx.x & (NB - 1);   // same-batch blocks are stride-32 -> same XCD under %8 round-robin
    const int c = blockIdx.x >> 5;
    const int t = threadIdx.x;

    __shared__ unsigned long long wkey[THREADS / 64];  // per-wave argmax keys
    __shared__ float bc_x, bc_y, bc_z;

    const float* bpts = pts + (size_t)b * NPTS * 3;

    // Per-thread state fully in registers: 3x32 coords + 32 dists.
    float x[PPT], y[PPT], z[PPT], dist[PPT];
    #pragma unroll
    for (int i = 0; i < PPT; ++i) {
        const int n = c * CHUNK_PTS + i * THREADS + t;   // lane-consecutive -> coalesced
        x[i] = bpts[3 * n + 0];
        y[i] = bpts[3 * n + 1];
        z[i] = bpts[3 * n + 2];
        dist[i] = BIGF;
    }

    // First selected point is index 0.
    float px = bpts[0], py = bpts[1], pz = bpts[2];
    if (c == 0 && t == 0) {
        out[(size_t)b * NSAMP * 3 + 0] = px;
        out[(size_t)b * NSAMP * 3 + 1] = py;
        out[(size_t)b * NSAMP * 3 + 2] = pz;
    }

    for (int s = 1; s < NSAMP; ++s) {
        // --- distance update + thread-local argmax (pure VALU, static indices) ---
        float bv = -1.0f;
        int   bi = 0;
        #pragma unroll
        for (int i = 0; i < PPT; ++i) {
            const float dx = x[i] - px;
            const float dy = y[i] - py;
            const float dz = z[i] - pz;
            float d = dx * dx;
            d = d + dy * dy;
            d = d + dz * dz;
            const float nd = fminf(dist[i], d);
            dist[i] = nd;
            if (nd > bv) { bv = nd; bi = c * CHUNK_PTS + i * THREADS + t; }
            // strict '>' keeps earliest (lowest) index within the thread
        }

        // --- wave argmax (64 lanes), tie -> lower global index ---
        #pragma unroll
        for (int off = 32; off > 0; off >>= 1) {
            const float ov = __shfl_xor(bv, off);
            const int   oi = __shfl_xor(bi, off);
            if (ov > bv || (ov == bv && oi < bi)) { bv = ov; bi = oi; }
        }
        if ((t & 63) == 0) {
            wkey[t >> 6] = ((unsigned long long)__float_as_uint(bv) << 32)
                         | ((unsigned long long)(NPTS - 1 - bi) << 15)
                         | (unsigned long long)s;
        }
        __syncthreads();

        if (t < 64) {   // wave 0 handles the cross-block rendezvous
            // block argmax over the 8 wave keys via 8-lane butterfly
            unsigned long long k = (t < THREADS / 64) ? wkey[t] : 0ull;
            #pragma unroll
            for (int off = 1; off < 8; off <<= 1) {
                const unsigned long long ok = __shfl_xor(k, off);
                if (ok > k) k = ok;
            }
            // lanes 0..7 now all hold the block key
            unsigned long long* kslot = keys + ((size_t)(s & 1) * NB + b) * CHUNKS;
            if (t == 0)
                __hip_atomic_store(&kslot[c], k, __ATOMIC_RELAXED, __HIP_MEMORY_SCOPE_AGENT);
            __atomic_signal_fence(__ATOMIC_SEQ_CST);   // compiler-only: post must precede polls

            // lane j polls slot j (relaxed: no cache-maintenance per poll)
            unsigned long long pk = 0;
            if (t < CHUNKS) {
                do {
                    pk = __hip_atomic_load(&kslot[t], __ATOMIC_RELAXED, __HIP_MEMORY_SCOPE_AGENT);
                } while ((pk & SEQ_MASK) != (unsigned long long)s);
            }
            // global (per-batch) argmax over 8 chunk keys
            #pragma unroll
            for (int off = 1; off < 8; off <<= 1) {
                const unsigned long long ok = __shfl_xor(pk, off);
                if (ok > pk) pk = ok;
            }
            if (t == 0) {
                const int widx = (NPTS - 1) - (int)((pk >> 15) & 0x1FFFF);
                const float wx = bpts[3 * (size_t)widx + 0];
                const float wy = bpts[3 * (size_t)widx + 1];
                const float wz = bpts[3 * (size_t)widx + 2];
                bc_x = wx; bc_y = wy; bc_z = wz;
                if (c == 0) {
                    const size_t o = ((size_t)b * NSAMP + s) * 3;
                    out[o + 0] = wx; out[o + 1] = wy; out[o + 2] = wz;
                }
            }
        }
        __syncthreads();
        px = bc_x; py = bc_y; pz = bc_z;
    }
}

extern "C" void kernel_launch(void* const* d_in, const int* in_sizes, int n_in,
                              void* d_out, int out_size, void* d_ws, size_t ws_size,
                              hipStream_t stream)
{
    const float* pts = (const float*)d_in[0];
    float* out = (float*)d_out;

    // keys[2][NB][CHUNKS] u64 = 4096 B. No init needed: 0xAA poison has
    // seq bits 0x2AAA which never equals any round number s <= 1023.
    unsigned long long* keys = (unsigned long long*)d_ws;

    fps_kernel<<<dim3(NB * CHUNKS), dim3(THREADS), 0, stream>>>(pts, out, keys);
}